// Round 9
// baseline (324.254 us; speedup 1.0000x reference)
//
#include <hip/hip_runtime.h>
#include <math.h>

// ---------------------------------------------------------------------------
// HeteroGNN forward. bf16 MFMA GEMM with fp32 A-load + inline cvt (mm1, merged
// with CSR fill) and inline BN+LeakyReLU (mm2); bf16 projected features; CSR
// mean-agg with type-split wave halves + chunk-4 ILP; hierarchical scan;
// BN stats via 256-block atomics; dense widening gather.
//   Wf (192 x F) = [ 0.5*(Wul0@Wd0 + Wul1@Wd1) ; 0.5*Wur0@Ws0 ; 0.5*Wur1@Ws1 ]
//   [h | P0 | P1] = x @ Wf^T   (h fp32, P bf16)
//   h[d] += mean_{csr0[d]} P0[src] + mean_{csr1[d]} P1[src]
//   BN(train, eps=1, biased) + LeakyReLU(0.01)
// ---------------------------------------------------------------------------

typedef float f32x4 __attribute__((ext_vector_type(4)));
typedef float f32x2 __attribute__((ext_vector_type(2)));
typedef short bf16x8 __attribute__((ext_vector_type(8)));
typedef unsigned short u16x4 __attribute__((ext_vector_type(4)));

#define NB_SCAN 64  // scan blocks per edge type

static __device__ __forceinline__ unsigned short f2bf(float f) {
  unsigned int u = __builtin_bit_cast(unsigned int, f);
  unsigned int r = (u + 0x7FFFu + ((u >> 16) & 1u)) >> 16;
  return (unsigned short)r;
}
static __device__ __forceinline__ float bfl(unsigned int u) {
  return __builtin_bit_cast(float, u << 16);
}
static __device__ __forceinline__ float bfh(unsigned int u) {
  return __builtin_bit_cast(float, u & 0xFFFF0000u);
}

// fusew1 (blocks [0,96)), fusew2 ([96,144)), zero cnt+stats ([144, 144+zb))
__global__ void prep_kernel(const float* __restrict__ Wd10, const float* __restrict__ Ws10,
                            const float* __restrict__ Wu10, const float* __restrict__ Wd11,
                            const float* __restrict__ Ws11, const float* __restrict__ Wu11,
                            unsigned short* __restrict__ Wfb1,
                            const float* __restrict__ Wd20, const float* __restrict__ Ws20,
                            const float* __restrict__ Wu20, const float* __restrict__ Wd21,
                            const float* __restrict__ Ws21, const float* __restrict__ Wu21,
                            unsigned short* __restrict__ Wfb2,
                            int* __restrict__ cnt0, int* __restrict__ cnt1,
                            float* __restrict__ s1, float* __restrict__ s2, int N) {
  int b = blockIdx.x;
  if (b >= 144) {
    int g = (b - 144) * 256 + threadIdx.x;
    if (g < N) { cnt0[g] = 0; cnt1[g] = 0; }
    if (g < 128) { s1[g] = 0.f; s2[g] = 0.f; }
    return;
  }
  const float *Wd0, *Ws0, *Wu0, *Wd1, *Ws1, *Wu1;
  unsigned short* Wfb;
  int K, gid;
  if (b < 96) {
    Wd0 = Wd10; Ws0 = Ws10; Wu0 = Wu10; Wd1 = Wd11; Ws1 = Ws11; Wu1 = Wu11;
    Wfb = Wfb1; K = 128;
    gid = b * 256 + threadIdx.x;
  } else {
    Wd0 = Wd20; Ws0 = Ws20; Wu0 = Wu20; Wd1 = Wd21; Ws1 = Ws21; Wu1 = Wu21;
    Wfb = Wfb2; K = 64;
    gid = (b - 96) * 256 + threadIdx.x;
  }
  if (gid >= 192 * K) return;
  int i = gid / K, j = gid - i * K;
  float s = 0.f;
  if (i < 64) {
#pragma unroll 4
    for (int k = 0; k < 64; ++k)
      s += Wu0[i * 128 + k] * Wd0[k * K + j] + Wu1[i * 128 + k] * Wd1[k * K + j];
  } else if (i < 128) {
    int ii = i - 64;
#pragma unroll 4
    for (int k = 0; k < 64; ++k) s += Wu0[ii * 128 + 64 + k] * Ws0[k * K + j];
  } else {
    int ii = i - 128;
#pragma unroll 4
    for (int k = 0; k < 64; ++k) s += Wu1[ii * 128 + 64 + k] * Ws1[k * K + j];
  }
  Wfb[gid] = f2bf(0.5f * s);
}

__global__ void count_both(const int* __restrict__ dst0, const int* __restrict__ dst1,
                           int* __restrict__ cnt0, int* __restrict__ cnt1, int E, int eg) {
  int b = blockIdx.x;
  bool t1 = b >= eg;
  int e = (t1 ? b - eg : b) * 256 + threadIdx.x;
  if (e >= E) return;
  if (t1) atomicAdd(&cnt1[dst1[e]], 1);
  else atomicAdd(&cnt0[dst0[e]], 1);
}

// scan stage A: per-block sums. 2*NB_SCAN blocks.
__global__ __launch_bounds__(256) void scanA(const int* __restrict__ cnt0,
                                             const int* __restrict__ cnt1,
                                             int* __restrict__ bsum, int N, int chunk) {
  int b = blockIdx.x;
  const int* cnt = (b < NB_SCAN) ? cnt0 : cnt1;
  int lb = (b < NB_SCAN) ? b : b - NB_SCAN;
  int lo = lb * chunk, hi = min(lo + chunk, N);
  int s = 0;
  for (int i = lo + threadIdx.x; i < hi; i += 256) s += cnt[i];
  __shared__ int red[256];
  red[threadIdx.x] = s;
  __syncthreads();
  for (int off = 128; off > 0; off >>= 1) {
    if (threadIdx.x < off) red[threadIdx.x] += red[threadIdx.x + off];
    __syncthreads();
  }
  if (threadIdx.x == 0) bsum[b] = red[0];
}

// scan stage C (with inline stage B): per-block local exclusive scan + base.
__global__ __launch_bounds__(256) void scanC(const int* __restrict__ cnt0,
                                             const int* __restrict__ cnt1,
                                             const int* __restrict__ bsum,
                                             int* __restrict__ base0, int* __restrict__ base1,
                                             int N, int chunk, int E) {
  int b = blockIdx.x;
  const int* cnt = (b < NB_SCAN) ? cnt0 : cnt1;
  int* base = (b < NB_SCAN) ? base0 : base1;
  int lb = (b < NB_SCAN) ? b : b - NB_SCAN;
  int lo = lb * chunk, hi = min(lo + chunk, N);
  int t = threadIdx.x;
  __shared__ int lsc[2 * NB_SCAN];
  __shared__ int run0s;
  if (t < 2 * NB_SCAN) lsc[t] = bsum[t];
  __syncthreads();
  if (t == 0) {
    int klo = (b < NB_SCAN) ? 0 : NB_SCAN;
    int r = 0;
    for (int k = klo; k < b; ++k) r += lsc[k];
    run0s = r;
  }
  __syncthreads();
  int v[4];
  int ls = 0;
  int i0 = lo + t * 4;
#pragma unroll
  for (int j = 0; j < 4; ++j) {
    v[j] = (i0 + j < hi) ? cnt[i0 + j] : 0;
    ls += v[j];
  }
  __shared__ int l[256];
  l[t] = ls;
  __syncthreads();
  for (int off = 1; off < 256; off <<= 1) {
    int x = l[t];
    if (t >= off) x += l[t - off];
    __syncthreads();
    l[t] = x;
    __syncthreads();
  }
  int run = run0s + l[t] - ls;
#pragma unroll
  for (int j = 0; j < 4; ++j) {
    if (i0 + j < hi) base[i0 + j] = run;
    run += v[j];
  }
  if (t == 0 && lb == NB_SCAN - 1) base[N] = E;
}

static __device__ __forceinline__ void fill_body(int b, const int* __restrict__ src0,
                                                 const int* __restrict__ dst0,
                                                 const int* __restrict__ base0,
                                                 int* __restrict__ cnt0, int* __restrict__ csr0,
                                                 const int* __restrict__ src1,
                                                 const int* __restrict__ dst1,
                                                 const int* __restrict__ base1,
                                                 int* __restrict__ cnt1, int* __restrict__ csr1,
                                                 int E, int eg) {
  bool t1 = b >= eg;
  int e = (t1 ? b - eg : b) * 256 + threadIdx.x;
  if (e >= E) return;
  const int* src = t1 ? src1 : src0;
  const int* dst = t1 ? dst1 : dst0;
  const int* base = t1 ? base1 : base0;
  int* cnt = t1 ? cnt1 : cnt0;
  int* csr = t1 ? csr1 : csr0;
  int d = dst[e];
  int p = atomicSub(&cnt[d], 1) - 1;
  csr[base[d] + p] = src[e];
}

// [h|P0|P1] = f(xa)[N,K] @ Wfb[192,K]^T.  A fp32; BN=false: plain cvt,
// BN=true: y=a*x+b', leaky(0.01). 64 rows/block, 4 waves x 48 cols.
template <int K, bool BN>
static __device__ __forceinline__ void mm_body(int bid, const float* __restrict__ xa,
                                               const unsigned short* __restrict__ Wfb,
                                               const float* __restrict__ stats,
                                               const float* __restrict__ gg,
                                               const float* __restrict__ bb, float invN,
                                               float* __restrict__ h,
                                               unsigned short* __restrict__ P0,
                                               unsigned short* __restrict__ P1, int N) {
  constexpr int NKS = K / 32;
  __shared__ float sa[64], sb[64];
  int tid = threadIdx.x;
  if constexpr (BN) {
    if (tid < 64) {
      float m = stats[tid] * invN;
      float v = stats[64 + tid] * invN - m * m;
      float a = gg[tid] * rsqrtf(v + 1.0f);
      sa[tid] = a;
      sb[tid] = bb[tid] - m * a;
    }
    __syncthreads();
  }
  int l = tid & 63;
  int wv = tid >> 6;
  int lr = l & 15;
  int lj = l >> 4;
  int brow = bid * 64;
  int wcol = wv * 48;

  bf16x8 B[3 * NKS];
#pragma unroll
  for (int ct = 0; ct < 3; ++ct)
#pragma unroll
    for (int ks = 0; ks < NKS; ++ks) {
      int col = wcol + ct * 16 + lr;
      B[ct * NKS + ks] = *(const bf16x8*)&Wfb[(size_t)col * K + ks * 32 + lj * 8];
    }

  f32x4 acc[4][3];
#pragma unroll
  for (int rt = 0; rt < 4; ++rt)
#pragma unroll
    for (int ct = 0; ct < 3; ++ct) acc[rt][ct] = (f32x4){0.f, 0.f, 0.f, 0.f};

#pragma unroll
  for (int ks = 0; ks < NKS; ++ks) {
    int colbase = ks * 32 + lj * 8;
    bf16x8 A[4];
#pragma unroll
    for (int rt = 0; rt < 4; ++rt) {
      int row = brow + rt * 16 + lr;
      if (row >= N) row = N - 1;
      const float* p = &xa[(size_t)row * K + colbase];
      f32x4 v0 = *(const f32x4*)p;
      f32x4 v1 = *(const f32x4*)(p + 4);
      bf16x8 r;
#pragma unroll
      for (int j = 0; j < 4; ++j) {
        float t0 = v0[j], t1 = v1[j];
        if constexpr (BN) {
          int c0 = colbase + j, c1 = colbase + 4 + j;
          t0 = fmaf(sa[c0], t0, sb[c0]);
          t0 = fmaxf(t0, 0.01f * t0);
          t1 = fmaf(sa[c1], t1, sb[c1]);
          t1 = fmaxf(t1, 0.01f * t1);
        }
        r[j] = (short)f2bf(t0);
        r[4 + j] = (short)f2bf(t1);
      }
      A[rt] = r;
    }
#pragma unroll
    for (int rt = 0; rt < 4; ++rt)
#pragma unroll
      for (int ct = 0; ct < 3; ++ct)
        acc[rt][ct] =
            __builtin_amdgcn_mfma_f32_16x16x32_bf16(A[rt], B[ct * NKS + ks], acc[rt][ct], 0, 0, 0);
  }

#pragma unroll
  for (int rt = 0; rt < 4; ++rt)
#pragma unroll
    for (int ct = 0; ct < 3; ++ct) {
      int gct = (wcol >> 4) + ct;
      int sel = gct >> 2;
      int c0 = (gct & 3) * 16 + lr;
#pragma unroll
      for (int r = 0; r < 4; ++r) {
        int row = brow + rt * 16 + lj * 4 + r;
        if (row < N) {
          if (sel == 0) h[(size_t)row * 64 + c0] = acc[rt][ct][r];
          else if (sel == 1) P0[(size_t)row * 64 + c0] = f2bf(acc[rt][ct][r]);
          else P1[(size_t)row * 64 + c0] = f2bf(acc[rt][ct][r]);
        }
      }
    }
}

// mm1 (blocks [0,mmB)) merged with CSR fill (blocks [mmB, mmB+2*eg)).
__global__ __launch_bounds__(256) void mm1_fill_kernel(
    const float* __restrict__ xa, const unsigned short* __restrict__ Wfb,
    float* __restrict__ h, unsigned short* __restrict__ P0, unsigned short* __restrict__ P1,
    int N, int mmB,
    const int* __restrict__ src0, const int* __restrict__ dst0, const int* __restrict__ base0,
    int* __restrict__ cnt0, int* __restrict__ csr0,
    const int* __restrict__ src1, const int* __restrict__ dst1, const int* __restrict__ base1,
    int* __restrict__ cnt1, int* __restrict__ csr1, int E, int eg) {
  int b = blockIdx.x;
  if (b < mmB) {
    mm_body<128, false>(b, xa, Wfb, nullptr, nullptr, nullptr, 0.f, h, P0, P1, N);
  } else {
    fill_body(b - mmB, src0, dst0, base0, cnt0, csr0, src1, dst1, base1, cnt1, csr1, E, eg);
  }
}

__global__ __launch_bounds__(256) void mm2_kernel(const float* __restrict__ xa,
                                                  const unsigned short* __restrict__ Wfb,
                                                  const float* __restrict__ stats,
                                                  const float* __restrict__ gg,
                                                  const float* __restrict__ bb, float invN,
                                                  float* __restrict__ h,
                                                  unsigned short* __restrict__ P0,
                                                  unsigned short* __restrict__ P1, int N) {
  mm_body<64, true>(blockIdx.x, xa, Wfb, stats, gg, bb, invN, h, P0, P1, N);
}

// 64 lanes per dst node: lanes 0-31 aggregate type 0, lanes 32-63 type 1
// (chunk-4 ILP each); halves combined via shfl_xor(32); lanes<32 RMW h.
__global__ void agg_kernel(float* __restrict__ h, const unsigned short* __restrict__ P0,
                           const unsigned short* __restrict__ P1,
                           const int* __restrict__ csr0, const int* __restrict__ base0,
                           const int* __restrict__ csr1, const int* __restrict__ base1,
                           int N) {
  int gid = blockIdx.x * blockDim.x + threadIdx.x;
  int w = gid >> 6;
  if (w >= N) return;
  int lane = threadIdx.x & 63;
  int c = lane & 31;
  int co = 2 * c;
  bool t1 = lane >= 32;
  const int* csr = t1 ? csr1 : csr0;
  const int* base = t1 ? base1 : base0;
  const unsigned short* P = t1 ? P1 : P0;
  int b0 = base[w], e0 = base[w + 1];
  float a0 = 0.f, a1 = 0.f, a2 = 0.f, a3 = 0.f;
  int i = b0;
  for (; i + 4 <= e0; i += 4) {
    int j0 = csr[i], j1 = csr[i + 1], j2 = csr[i + 2], j3 = csr[i + 3];
    unsigned int u0 = *(const unsigned int*)&P[(size_t)j0 * 64 + co];
    unsigned int u1 = *(const unsigned int*)&P[(size_t)j1 * 64 + co];
    unsigned int u2 = *(const unsigned int*)&P[(size_t)j2 * 64 + co];
    unsigned int u3 = *(const unsigned int*)&P[(size_t)j3 * 64 + co];
    a0 += bfl(u0); a1 += bfh(u0);
    a2 += bfl(u1); a3 += bfh(u1);
    a0 += bfl(u2); a1 += bfh(u2);
    a2 += bfl(u3); a3 += bfh(u3);
  }
  for (; i < e0; ++i) {
    unsigned int u = *(const unsigned int*)&P[(size_t)csr[i] * 64 + co];
    a0 += bfl(u); a1 += bfh(u);
  }
  float iv = 1.0f / fmaxf((float)(e0 - b0), 1.0f);
  float s0 = (a0 + a2) * iv;
  float s1 = (a1 + a3) * iv;
  // combine type halves: lane<32 gets its own (t0) + partner's (t1) part
  float o0 = __shfl_xor(s0, 32);
  float o1 = __shfl_xor(s1, 32);
  if (!t1) {
    f32x2* hp = (f32x2*)&h[(size_t)w * 64 + co];
    f32x2 hv = *hp;
    hv.x += s0 + o0;
    hv.y += s1 + o1;
    *hp = hv;
  }
}

__global__ __launch_bounds__(256) void bnstats_kernel(const float* __restrict__ h,
                                                      float* __restrict__ stats, int N) {
  int tid = threadIdx.x;
  int c = tid & 63;
  int part = tid >> 6;
  float s = 0.f, s2 = 0.f;
  for (int r = blockIdx.x * 4 + part; r < N; r += gridDim.x * 4) {
    float v = h[(size_t)r * 64 + c];
    s += v;
    s2 += v * v;
  }
  __shared__ float red[512];
  red[tid] = s;
  red[256 + tid] = s2;
  __syncthreads();
  if (part == 0) {
    s = red[c] + red[64 + c] + red[128 + c] + red[192 + c];
    s2 = red[256 + c] + red[256 + 64 + c] + red[256 + 128 + c] + red[256 + 192 + c];
    atomicAdd(&stats[c], s);
    atomicAdd(&stats[64 + c], s2);
  }
}

// h fp32 -> bf16 activated features (BN + leaky); a/b derived in-block.
__global__ void bnapply_kernel(const float* __restrict__ h, const float* __restrict__ stats,
                               const float* __restrict__ gg, const float* __restrict__ bb,
                               float invN, unsigned short* __restrict__ xo, int N) {
  __shared__ float sa[64], sb[64];
  if (threadIdx.x < 64) {
    int c = threadIdx.x;
    float m = stats[c] * invN;
    float v = stats[64 + c] * invN - m * m;
    float a = gg[c] * rsqrtf(v + 1.0f);
    sa[c] = a;
    sb[c] = bb[c] - m * a;
  }
  __syncthreads();
  int gid = blockIdx.x * blockDim.x + threadIdx.x;
  if (gid >= N * 16) return;
  f32x4 v = ((const f32x4*)h)[gid];
  int c = (gid & 15) * 4;
  u16x4 o;
#pragma unroll
  for (int j = 0; j < 4; ++j) {
    float t = fmaf(sa[c + j], v[j], sb[c + j]);
    o[j] = f2bf(fmaxf(t, 0.01f * t));
  }
  ((u16x4*)xo)[gid] = o;
}

// widening gather: out[row]=[xc[src]||xc[dst]] fp32; 32 threads/row,
// each reads u16x4 (8B) and writes ONE dense f32x4 (16B) -> fully coalesced.
__global__ void gather_kernel(const unsigned short* __restrict__ xc,
                              const int* __restrict__ src0, const int* __restrict__ dst0,
                              const int* __restrict__ src1, const int* __restrict__ dst1,
                              float* __restrict__ out, int E) {
  int gid = blockIdx.x * blockDim.x + threadIdx.x;
  int total = 2 * E * 32;
  if (gid >= total) return;
  int row = gid >> 5, q = gid & 31;
  int e, s, d;
  if (row < E) {
    e = row; s = src0[e]; d = dst0[e];
  } else {
    e = row - E; s = src1[e]; d = dst1[e];
  }
  int node = (q < 16) ? s : d;
  int qq = q & 15;
  u16x4 v = *(const u16x4*)&xc[(size_t)node * 64 + qq * 4];
  f32x4 o;
#pragma unroll
  for (int j = 0; j < 4; ++j) o[j] = bfl((unsigned int)v[j]);
  __builtin_nontemporal_store(o, (f32x4*)out + gid);
}

extern "C" void kernel_launch(void* const* d_in, const int* in_sizes, int n_in,
                              void* d_out, int out_size, void* d_ws, size_t ws_size,
                              hipStream_t stream) {
  const float* x0 = (const float*)d_in[0];
  const int* ei0 = (const int*)d_in[1];
  const int* ei1 = (const int*)d_in[2];
  const float* bn1_g = (const float*)d_in[15];
  const float* bn1_b = (const float*)d_in[16];
  const float* bn2_g = (const float*)d_in[17];
  const float* bn2_b = (const float*)d_in[18];

  const int N = in_sizes[0] / 128;
  const int E = in_sizes[1] / 2;
  const int *src0 = ei0, *dst0 = ei0 + E;
  const int *src1 = ei1, *dst1 = ei1 + E;

  char* wsb = (char*)d_ws;
  size_t off = 0;
  auto alloc = [&](size_t bytes) {
    char* p = wsb + off;
    off = (off + bytes + 255) & ~(size_t)255;
    return (void*)p;
  };
  unsigned short* Wfb1 = (unsigned short*)alloc(192 * 128 * 2);
  unsigned short* Wfb2 = (unsigned short*)alloc(192 * 64 * 2);
  float* stats1 = (float*)alloc(128 * 4);
  float* stats2 = (float*)alloc(128 * 4);
  int* bsum = (int*)alloc(2 * NB_SCAN * 4);
  int* cnt0 = (int*)alloc((size_t)N * 4);
  int* cnt1 = (int*)alloc((size_t)N * 4);
  int* base0 = (int*)alloc(((size_t)N + 1) * 4);
  int* base1 = (int*)alloc(((size_t)N + 1) * 4);
  int* csr0 = (int*)alloc((size_t)E * 4);
  int* csr1 = (int*)alloc((size_t)E * 4);
  float* h = (float*)alloc((size_t)N * 64 * 4);
  float* h2 = (float*)alloc((size_t)N * 64 * 4);
  unsigned short* P0 = (unsigned short*)alloc((size_t)N * 64 * 2);
  unsigned short* P1 = (unsigned short*)alloc((size_t)N * 64 * 2);
  unsigned short* xc2 = (unsigned short*)alloc((size_t)N * 64 * 2);

  const float invN = 1.0f / (float)N;
  const int eg = (E + 255) / 256;
  const int chunk = (N + NB_SCAN - 1) / NB_SCAN;
  const int zb = (N + 255) / 256;

  prep_kernel<<<144 + zb, 256, 0, stream>>>(
      (const float*)d_in[3], (const float*)d_in[4], (const float*)d_in[5],
      (const float*)d_in[6], (const float*)d_in[7], (const float*)d_in[8], Wfb1,
      (const float*)d_in[9], (const float*)d_in[10], (const float*)d_in[11],
      (const float*)d_in[12], (const float*)d_in[13], (const float*)d_in[14], Wfb2,
      cnt0, cnt1, stats1, stats2, N);
  count_both<<<2 * eg, 256, 0, stream>>>(dst0, dst1, cnt0, cnt1, E, eg);
  scanA<<<2 * NB_SCAN, 256, 0, stream>>>(cnt0, cnt1, bsum, N, chunk);
  scanC<<<2 * NB_SCAN, 256, 0, stream>>>(cnt0, cnt1, bsum, base0, base1, N, chunk, E);

  const int mmGrid = (N + 63) / 64;
  const int aggGrid = (N * 64 + 255) / 256;

  // mm1 (A = x0 fp32, cvt inline) merged with CSR fill
  mm1_fill_kernel<<<mmGrid + 2 * eg, 256, 0, stream>>>(
      x0, Wfb1, h, P0, P1, N, mmGrid,
      src0, dst0, base0, cnt0, csr0, src1, dst1, base1, cnt1, csr1, E, eg);
  agg_kernel<<<aggGrid, 256, 0, stream>>>(h, P0, P1, csr0, base0, csr1, base1, N);
  bnstats_kernel<<<256, 256, 0, stream>>>(h, stats1, N);

  // layer 2 (A = h fp32, BN1+leaky inline)
  mm2_kernel<<<mmGrid, 256, 0, stream>>>(h, Wfb2, stats1, bn1_g, bn1_b, invN, h2, P0, P1, N);
  agg_kernel<<<aggGrid, 256, 0, stream>>>(h2, P0, P1, csr0, base0, csr1, base1, N);
  bnstats_kernel<<<256, 256, 0, stream>>>(h2, stats2, N);
  bnapply_kernel<<<(N * 16 + 255) / 256, 256, 0, stream>>>(h2, stats2, bn2_g, bn2_b, invN,
                                                           xc2, N);

  // output gather (dense coalesced widen-copy)
  gather_kernel<<<(2 * E * 32 + 255) / 256, 256, 0, stream>>>(
      xc2, src0, dst0, src1, dst1, (float*)d_out, E);
}

// Round 10
// 314.876 us; speedup vs baseline: 1.0298x; 1.0298x over previous
//
#include <hip/hip_runtime.h>
#include <math.h>

// ---------------------------------------------------------------------------
// HeteroGNN forward. bf16 MFMA GEMM with fp32 A-load + inline cvt (mm1) and
// inline BN+LeakyReLU (mm2); bf16 projected features; CSR mean-agg with
// dual-type interleaved chunk-4 ILP (8 gathers in flight per half-wave);
// hierarchical scan; BN stats via 256-block atomics; dense widening gather.
//   Wf (192 x F) = [ 0.5*(Wul0@Wd0 + Wul1@Wd1) ; 0.5*Wur0@Ws0 ; 0.5*Wur1@Ws1 ]
//   [h | P0 | P1] = x @ Wf^T   (h fp32, P bf16)
//   h[d] += mean_{csr0[d]} P0[src] + mean_{csr1[d]} P1[src]
//   BN(train, eps=1, biased) + LeakyReLU(0.01)
// ---------------------------------------------------------------------------

typedef float f32x4 __attribute__((ext_vector_type(4)));
typedef float f32x2 __attribute__((ext_vector_type(2)));
typedef short bf16x8 __attribute__((ext_vector_type(8)));
typedef unsigned short u16x4 __attribute__((ext_vector_type(4)));

#define NB_SCAN 64  // scan blocks per edge type

static __device__ __forceinline__ unsigned short f2bf(float f) {
  unsigned int u = __builtin_bit_cast(unsigned int, f);
  unsigned int r = (u + 0x7FFFu + ((u >> 16) & 1u)) >> 16;
  return (unsigned short)r;
}
static __device__ __forceinline__ float bfl(unsigned int u) {
  return __builtin_bit_cast(float, u << 16);
}
static __device__ __forceinline__ float bfh(unsigned int u) {
  return __builtin_bit_cast(float, u & 0xFFFF0000u);
}

// fusew1 (blocks [0,96)), fusew2 ([96,144)), zero cnt+stats ([144, 144+zb))
__global__ void prep_kernel(const float* __restrict__ Wd10, const float* __restrict__ Ws10,
                            const float* __restrict__ Wu10, const float* __restrict__ Wd11,
                            const float* __restrict__ Ws11, const float* __restrict__ Wu11,
                            unsigned short* __restrict__ Wfb1,
                            const float* __restrict__ Wd20, const float* __restrict__ Ws20,
                            const float* __restrict__ Wu20, const float* __restrict__ Wd21,
                            const float* __restrict__ Ws21, const float* __restrict__ Wu21,
                            unsigned short* __restrict__ Wfb2,
                            int* __restrict__ cnt0, int* __restrict__ cnt1,
                            float* __restrict__ s1, float* __restrict__ s2, int N) {
  int b = blockIdx.x;
  if (b >= 144) {
    int g = (b - 144) * 256 + threadIdx.x;
    if (g < N) { cnt0[g] = 0; cnt1[g] = 0; }
    if (g < 128) { s1[g] = 0.f; s2[g] = 0.f; }
    return;
  }
  const float *Wd0, *Ws0, *Wu0, *Wd1, *Ws1, *Wu1;
  unsigned short* Wfb;
  int K, gid;
  if (b < 96) {
    Wd0 = Wd10; Ws0 = Ws10; Wu0 = Wu10; Wd1 = Wd11; Ws1 = Ws11; Wu1 = Wu11;
    Wfb = Wfb1; K = 128;
    gid = b * 256 + threadIdx.x;
  } else {
    Wd0 = Wd20; Ws0 = Ws20; Wu0 = Wu20; Wd1 = Wd21; Ws1 = Ws21; Wu1 = Wu21;
    Wfb = Wfb2; K = 64;
    gid = (b - 96) * 256 + threadIdx.x;
  }
  if (gid >= 192 * K) return;
  int i = gid / K, j = gid - i * K;
  float s = 0.f;
  if (i < 64) {
#pragma unroll 4
    for (int k = 0; k < 64; ++k)
      s += Wu0[i * 128 + k] * Wd0[k * K + j] + Wu1[i * 128 + k] * Wd1[k * K + j];
  } else if (i < 128) {
    int ii = i - 64;
#pragma unroll 4
    for (int k = 0; k < 64; ++k) s += Wu0[ii * 128 + 64 + k] * Ws0[k * K + j];
  } else {
    int ii = i - 128;
#pragma unroll 4
    for (int k = 0; k < 64; ++k) s += Wu1[ii * 128 + 64 + k] * Ws1[k * K + j];
  }
  Wfb[gid] = f2bf(0.5f * s);
}

__global__ void count_both(const int* __restrict__ dst0, const int* __restrict__ dst1,
                           int* __restrict__ cnt0, int* __restrict__ cnt1, int E, int eg) {
  int b = blockIdx.x;
  bool t1 = b >= eg;
  int e = (t1 ? b - eg : b) * 256 + threadIdx.x;
  if (e >= E) return;
  if (t1) atomicAdd(&cnt1[dst1[e]], 1);
  else atomicAdd(&cnt0[dst0[e]], 1);
}

// scan stage A: per-block sums. 2*NB_SCAN blocks.
__global__ __launch_bounds__(256) void scanA(const int* __restrict__ cnt0,
                                             const int* __restrict__ cnt1,
                                             int* __restrict__ bsum, int N, int chunk) {
  int b = blockIdx.x;
  const int* cnt = (b < NB_SCAN) ? cnt0 : cnt1;
  int lb = (b < NB_SCAN) ? b : b - NB_SCAN;
  int lo = lb * chunk, hi = min(lo + chunk, N);
  int s = 0;
  for (int i = lo + threadIdx.x; i < hi; i += 256) s += cnt[i];
  __shared__ int red[256];
  red[threadIdx.x] = s;
  __syncthreads();
  for (int off = 128; off > 0; off >>= 1) {
    if (threadIdx.x < off) red[threadIdx.x] += red[threadIdx.x + off];
    __syncthreads();
  }
  if (threadIdx.x == 0) bsum[b] = red[0];
}

// scan stage C (with inline stage B): per-block local exclusive scan + base.
__global__ __launch_bounds__(256) void scanC(const int* __restrict__ cnt0,
                                             const int* __restrict__ cnt1,
                                             const int* __restrict__ bsum,
                                             int* __restrict__ base0, int* __restrict__ base1,
                                             int N, int chunk, int E) {
  int b = blockIdx.x;
  const int* cnt = (b < NB_SCAN) ? cnt0 : cnt1;
  int* base = (b < NB_SCAN) ? base0 : base1;
  int lb = (b < NB_SCAN) ? b : b - NB_SCAN;
  int lo = lb * chunk, hi = min(lo + chunk, N);
  int t = threadIdx.x;
  __shared__ int lsc[2 * NB_SCAN];
  __shared__ int run0s;
  if (t < 2 * NB_SCAN) lsc[t] = bsum[t];
  __syncthreads();
  if (t == 0) {
    int klo = (b < NB_SCAN) ? 0 : NB_SCAN;
    int r = 0;
    for (int k = klo; k < b; ++k) r += lsc[k];
    run0s = r;
  }
  __syncthreads();
  int v[4];
  int ls = 0;
  int i0 = lo + t * 4;
#pragma unroll
  for (int j = 0; j < 4; ++j) {
    v[j] = (i0 + j < hi) ? cnt[i0 + j] : 0;
    ls += v[j];
  }
  __shared__ int l[256];
  l[t] = ls;
  __syncthreads();
  for (int off = 1; off < 256; off <<= 1) {
    int x = l[t];
    if (t >= off) x += l[t - off];
    __syncthreads();
    l[t] = x;
    __syncthreads();
  }
  int run = run0s + l[t] - ls;
#pragma unroll
  for (int j = 0; j < 4; ++j) {
    if (i0 + j < hi) base[i0 + j] = run;
    run += v[j];
  }
  if (t == 0 && lb == NB_SCAN - 1) base[N] = E;
}

__global__ void fill_both(const int* __restrict__ src0, const int* __restrict__ dst0,
                          const int* __restrict__ base0, int* __restrict__ cnt0,
                          int* __restrict__ csr0,
                          const int* __restrict__ src1, const int* __restrict__ dst1,
                          const int* __restrict__ base1, int* __restrict__ cnt1,
                          int* __restrict__ csr1, int E, int eg) {
  int b = blockIdx.x;
  bool t1 = b >= eg;
  int e = (t1 ? b - eg : b) * 256 + threadIdx.x;
  if (e >= E) return;
  const int* src = t1 ? src1 : src0;
  const int* dst = t1 ? dst1 : dst0;
  const int* base = t1 ? base1 : base0;
  int* cnt = t1 ? cnt1 : cnt0;
  int* csr = t1 ? csr1 : csr0;
  int d = dst[e];
  int p = atomicSub(&cnt[d], 1) - 1;
  csr[base[d] + p] = src[e];
}

// [h|P0|P1] = f(xa)[N,K] @ Wfb[192,K]^T.  A is fp32; BN=false: plain cvt,
// BN=true: y = a*x+b', leaky(0.01) (a,b' derived in-block from raw sums).
// 64 rows/block, 4 waves x 48 cols.
template <int K, bool BN>
__global__ __launch_bounds__(256) void mm_mfma(const float* __restrict__ xa,
                                               const unsigned short* __restrict__ Wfb,
                                               const float* __restrict__ stats,
                                               const float* __restrict__ gg,
                                               const float* __restrict__ bb, float invN,
                                               float* __restrict__ h,
                                               unsigned short* __restrict__ P0,
                                               unsigned short* __restrict__ P1, int N) {
  constexpr int NKS = K / 32;
  __shared__ float sa[64], sb[64];
  int tid = threadIdx.x;
  if constexpr (BN) {
    if (tid < 64) {
      float m = stats[tid] * invN;
      float v = stats[64 + tid] * invN - m * m;
      float a = gg[tid] * rsqrtf(v + 1.0f);
      sa[tid] = a;
      sb[tid] = bb[tid] - m * a;
    }
    __syncthreads();
  }
  int l = tid & 63;
  int wv = tid >> 6;
  int lr = l & 15;
  int lj = l >> 4;
  int brow = blockIdx.x * 64;
  int wcol = wv * 48;

  bf16x8 B[3 * NKS];
#pragma unroll
  for (int ct = 0; ct < 3; ++ct)
#pragma unroll
    for (int ks = 0; ks < NKS; ++ks) {
      int col = wcol + ct * 16 + lr;
      B[ct * NKS + ks] = *(const bf16x8*)&Wfb[(size_t)col * K + ks * 32 + lj * 8];
    }

  f32x4 acc[4][3];
#pragma unroll
  for (int rt = 0; rt < 4; ++rt)
#pragma unroll
    for (int ct = 0; ct < 3; ++ct) acc[rt][ct] = (f32x4){0.f, 0.f, 0.f, 0.f};

#pragma unroll
  for (int ks = 0; ks < NKS; ++ks) {
    int colbase = ks * 32 + lj * 8;
    bf16x8 A[4];
#pragma unroll
    for (int rt = 0; rt < 4; ++rt) {
      int row = brow + rt * 16 + lr;
      if (row >= N) row = N - 1;
      const float* p = &xa[(size_t)row * K + colbase];
      f32x4 v0 = *(const f32x4*)p;
      f32x4 v1 = *(const f32x4*)(p + 4);
      bf16x8 r;
#pragma unroll
      for (int j = 0; j < 4; ++j) {
        float t0 = v0[j], t1 = v1[j];
        if constexpr (BN) {
          int c0 = colbase + j, c1 = colbase + 4 + j;
          t0 = fmaf(sa[c0], t0, sb[c0]);
          t0 = fmaxf(t0, 0.01f * t0);
          t1 = fmaf(sa[c1], t1, sb[c1]);
          t1 = fmaxf(t1, 0.01f * t1);
        }
        r[j] = (short)f2bf(t0);
        r[4 + j] = (short)f2bf(t1);
      }
      A[rt] = r;
    }
#pragma unroll
    for (int rt = 0; rt < 4; ++rt)
#pragma unroll
      for (int ct = 0; ct < 3; ++ct)
        acc[rt][ct] =
            __builtin_amdgcn_mfma_f32_16x16x32_bf16(A[rt], B[ct * NKS + ks], acc[rt][ct], 0, 0, 0);
  }

#pragma unroll
  for (int rt = 0; rt < 4; ++rt)
#pragma unroll
    for (int ct = 0; ct < 3; ++ct) {
      int gct = (wcol >> 4) + ct;
      int sel = gct >> 2;
      int c0 = (gct & 3) * 16 + lr;
#pragma unroll
      for (int r = 0; r < 4; ++r) {
        int row = brow + rt * 16 + lj * 4 + r;
        if (row < N) {
          if (sel == 0) h[(size_t)row * 64 + c0] = acc[rt][ct][r];
          else if (sel == 1) P0[(size_t)row * 64 + c0] = f2bf(acc[rt][ct][r]);
          else P1[(size_t)row * 64 + c0] = f2bf(acc[rt][ct][r]);
        }
      }
    }
}

// half-wave (32 lanes, 2 ch/lane) per dst node. Dual-type interleaved chunk-4:
// common phase issues 4 type-0 + 4 type-1 gathers per iteration (8 in flight),
// then per-type chunk-4 + scalar drains. Per-type accumulation order is
// identical to the round-8 version (bit-identical results).
__global__ void agg_kernel(float* __restrict__ h, const unsigned short* __restrict__ P0,
                           const unsigned short* __restrict__ P1,
                           const int* __restrict__ csr0, const int* __restrict__ base0,
                           const int* __restrict__ csr1, const int* __restrict__ base1,
                           int N) {
  int gid = blockIdx.x * blockDim.x + threadIdx.x;
  int w = gid >> 5, c = gid & 31;
  if (w >= N) return;
  int co = 2 * c;
  int i0 = base0[w], e0 = base0[w + 1];
  int i1 = base1[w], e1 = base1[w + 1];
  int n0 = e0 - i0, n1 = e1 - i1;
  float x0 = 0.f, x1 = 0.f, x2 = 0.f, x3 = 0.f;  // type-0 accumulators
  float y0 = 0.f, y1 = 0.f, y2 = 0.f, y3 = 0.f;  // type-1 accumulators
  // interleaved common phase: 8 independent gathers in flight
  while (i0 + 4 <= e0 && i1 + 4 <= e1) {
    int a_0 = csr0[i0], a_1 = csr0[i0 + 1], a_2 = csr0[i0 + 2], a_3 = csr0[i0 + 3];
    int b_0 = csr1[i1], b_1 = csr1[i1 + 1], b_2 = csr1[i1 + 2], b_3 = csr1[i1 + 3];
    unsigned int u0 = *(const unsigned int*)&P0[(size_t)a_0 * 64 + co];
    unsigned int u1 = *(const unsigned int*)&P0[(size_t)a_1 * 64 + co];
    unsigned int u2 = *(const unsigned int*)&P0[(size_t)a_2 * 64 + co];
    unsigned int u3 = *(const unsigned int*)&P0[(size_t)a_3 * 64 + co];
    unsigned int v0 = *(const unsigned int*)&P1[(size_t)b_0 * 64 + co];
    unsigned int v1 = *(const unsigned int*)&P1[(size_t)b_1 * 64 + co];
    unsigned int v2 = *(const unsigned int*)&P1[(size_t)b_2 * 64 + co];
    unsigned int v3 = *(const unsigned int*)&P1[(size_t)b_3 * 64 + co];
    x0 += bfl(u0); x1 += bfh(u0);
    x2 += bfl(u1); x3 += bfh(u1);
    x0 += bfl(u2); x1 += bfh(u2);
    x2 += bfl(u3); x3 += bfh(u3);
    y0 += bfl(v0); y1 += bfh(v0);
    y2 += bfl(v1); y3 += bfh(v1);
    y0 += bfl(v2); y1 += bfh(v2);
    y2 += bfl(v3); y3 += bfh(v3);
    i0 += 4;
    i1 += 4;
  }
  // drain type 0
  for (; i0 + 4 <= e0; i0 += 4) {
    int a_0 = csr0[i0], a_1 = csr0[i0 + 1], a_2 = csr0[i0 + 2], a_3 = csr0[i0 + 3];
    unsigned int u0 = *(const unsigned int*)&P0[(size_t)a_0 * 64 + co];
    unsigned int u1 = *(const unsigned int*)&P0[(size_t)a_1 * 64 + co];
    unsigned int u2 = *(const unsigned int*)&P0[(size_t)a_2 * 64 + co];
    unsigned int u3 = *(const unsigned int*)&P0[(size_t)a_3 * 64 + co];
    x0 += bfl(u0); x1 += bfh(u0);
    x2 += bfl(u1); x3 += bfh(u1);
    x0 += bfl(u2); x1 += bfh(u2);
    x2 += bfl(u3); x3 += bfh(u3);
  }
  for (; i0 < e0; ++i0) {
    unsigned int u = *(const unsigned int*)&P0[(size_t)csr0[i0] * 64 + co];
    x0 += bfl(u); x1 += bfh(u);
  }
  // drain type 1
  for (; i1 + 4 <= e1; i1 += 4) {
    int b_0 = csr1[i1], b_1 = csr1[i1 + 1], b_2 = csr1[i1 + 2], b_3 = csr1[i1 + 3];
    unsigned int v0 = *(const unsigned int*)&P1[(size_t)b_0 * 64 + co];
    unsigned int v1 = *(const unsigned int*)&P1[(size_t)b_1 * 64 + co];
    unsigned int v2 = *(const unsigned int*)&P1[(size_t)b_2 * 64 + co];
    unsigned int v3 = *(const unsigned int*)&P1[(size_t)b_3 * 64 + co];
    y0 += bfl(v0); y1 += bfh(v0);
    y2 += bfl(v1); y3 += bfh(v1);
    y0 += bfl(v2); y1 += bfh(v2);
    y2 += bfl(v3); y3 += bfh(v3);
  }
  for (; i1 < e1; ++i1) {
    unsigned int v = *(const unsigned int*)&P1[(size_t)csr1[i1] * 64 + co];
    y0 += bfl(v); y1 += bfh(v);
  }
  float iv0 = 1.0f / fmaxf((float)n0, 1.0f);
  float iv1 = 1.0f / fmaxf((float)n1, 1.0f);
  float s0 = (x0 + x2) * iv0 + (y0 + y2) * iv1;
  float s1 = (x1 + x3) * iv0 + (y1 + y3) * iv1;
  f32x2* hp = (f32x2*)&h[(size_t)w * 64 + co];
  f32x2 hv = *hp;
  hv.x += s0;
  hv.y += s1;
  *hp = hv;
}

__global__ __launch_bounds__(256) void bnstats_kernel(const float* __restrict__ h,
                                                      float* __restrict__ stats, int N) {
  int tid = threadIdx.x;
  int c = tid & 63;
  int part = tid >> 6;
  float s = 0.f, s2 = 0.f;
  for (int r = blockIdx.x * 4 + part; r < N; r += gridDim.x * 4) {
    float v = h[(size_t)r * 64 + c];
    s += v;
    s2 += v * v;
  }
  __shared__ float red[512];
  red[tid] = s;
  red[256 + tid] = s2;
  __syncthreads();
  if (part == 0) {
    s = red[c] + red[64 + c] + red[128 + c] + red[192 + c];
    s2 = red[256 + c] + red[256 + 64 + c] + red[256 + 128 + c] + red[256 + 192 + c];
    atomicAdd(&stats[c], s);
    atomicAdd(&stats[64 + c], s2);
  }
}

// h fp32 -> bf16 activated features (BN + leaky); a/b derived in-block.
__global__ void bnapply_kernel(const float* __restrict__ h, const float* __restrict__ stats,
                               const float* __restrict__ gg, const float* __restrict__ bb,
                               float invN, unsigned short* __restrict__ xo, int N) {
  __shared__ float sa[64], sb[64];
  if (threadIdx.x < 64) {
    int c = threadIdx.x;
    float m = stats[c] * invN;
    float v = stats[64 + c] * invN - m * m;
    float a = gg[c] * rsqrtf(v + 1.0f);
    sa[c] = a;
    sb[c] = bb[c] - m * a;
  }
  __syncthreads();
  int gid = blockIdx.x * blockDim.x + threadIdx.x;
  if (gid >= N * 16) return;
  f32x4 v = ((const f32x4*)h)[gid];
  int c = (gid & 15) * 4;
  u16x4 o;
#pragma unroll
  for (int j = 0; j < 4; ++j) {
    float t = fmaf(sa[c + j], v[j], sb[c + j]);
    o[j] = f2bf(fmaxf(t, 0.01f * t));
  }
  ((u16x4*)xo)[gid] = o;
}

// widening gather: out[row]=[xc[src]||xc[dst]] fp32; 32 threads/row,
// each reads u16x4 (8B) and writes ONE dense f32x4 (16B) -> fully coalesced.
__global__ void gather_kernel(const unsigned short* __restrict__ xc,
                              const int* __restrict__ src0, const int* __restrict__ dst0,
                              const int* __restrict__ src1, const int* __restrict__ dst1,
                              float* __restrict__ out, int E) {
  int gid = blockIdx.x * blockDim.x + threadIdx.x;
  int total = 2 * E * 32;
  if (gid >= total) return;
  int row = gid >> 5, q = gid & 31;
  int e, s, d;
  if (row < E) {
    e = row; s = src0[e]; d = dst0[e];
  } else {
    e = row - E; s = src1[e]; d = dst1[e];
  }
  int node = (q < 16) ? s : d;
  int qq = q & 15;
  u16x4 v = *(const u16x4*)&xc[(size_t)node * 64 + qq * 4];
  f32x4 o;
#pragma unroll
  for (int j = 0; j < 4; ++j) o[j] = bfl((unsigned int)v[j]);
  __builtin_nontemporal_store(o, (f32x4*)out + gid);
}

extern "C" void kernel_launch(void* const* d_in, const int* in_sizes, int n_in,
                              void* d_out, int out_size, void* d_ws, size_t ws_size,
                              hipStream_t stream) {
  const float* x0 = (const float*)d_in[0];
  const int* ei0 = (const int*)d_in[1];
  const int* ei1 = (const int*)d_in[2];
  const float* bn1_g = (const float*)d_in[15];
  const float* bn1_b = (const float*)d_in[16];
  const float* bn2_g = (const float*)d_in[17];
  const float* bn2_b = (const float*)d_in[18];

  const int N = in_sizes[0] / 128;
  const int E = in_sizes[1] / 2;
  const int *src0 = ei0, *dst0 = ei0 + E;
  const int *src1 = ei1, *dst1 = ei1 + E;

  char* wsb = (char*)d_ws;
  size_t off = 0;
  auto alloc = [&](size_t bytes) {
    char* p = wsb + off;
    off = (off + bytes + 255) & ~(size_t)255;
    return (void*)p;
  };
  unsigned short* Wfb1 = (unsigned short*)alloc(192 * 128 * 2);
  unsigned short* Wfb2 = (unsigned short*)alloc(192 * 64 * 2);
  float* stats1 = (float*)alloc(128 * 4);
  float* stats2 = (float*)alloc(128 * 4);
  int* bsum = (int*)alloc(2 * NB_SCAN * 4);
  int* cnt0 = (int*)alloc((size_t)N * 4);
  int* cnt1 = (int*)alloc((size_t)N * 4);
  int* base0 = (int*)alloc(((size_t)N + 1) * 4);
  int* base1 = (int*)alloc(((size_t)N + 1) * 4);
  int* csr0 = (int*)alloc((size_t)E * 4);
  int* csr1 = (int*)alloc((size_t)E * 4);
  float* h = (float*)alloc((size_t)N * 64 * 4);
  float* h2 = (float*)alloc((size_t)N * 64 * 4);
  unsigned short* P0 = (unsigned short*)alloc((size_t)N * 64 * 2);
  unsigned short* P1 = (unsigned short*)alloc((size_t)N * 64 * 2);
  unsigned short* xc2 = (unsigned short*)alloc((size_t)N * 64 * 2);

  const float invN = 1.0f / (float)N;
  const int eg = (E + 255) / 256;
  const int chunk = (N + NB_SCAN - 1) / NB_SCAN;
  const int zb = (N + 255) / 256;

  prep_kernel<<<144 + zb, 256, 0, stream>>>(
      (const float*)d_in[3], (const float*)d_in[4], (const float*)d_in[5],
      (const float*)d_in[6], (const float*)d_in[7], (const float*)d_in[8], Wfb1,
      (const float*)d_in[9], (const float*)d_in[10], (const float*)d_in[11],
      (const float*)d_in[12], (const float*)d_in[13], (const float*)d_in[14], Wfb2,
      cnt0, cnt1, stats1, stats2, N);
  count_both<<<2 * eg, 256, 0, stream>>>(dst0, dst1, cnt0, cnt1, E, eg);
  scanA<<<2 * NB_SCAN, 256, 0, stream>>>(cnt0, cnt1, bsum, N, chunk);
  scanC<<<2 * NB_SCAN, 256, 0, stream>>>(cnt0, cnt1, bsum, base0, base1, N, chunk, E);
  fill_both<<<2 * eg, 256, 0, stream>>>(src0, dst0, base0, cnt0, csr0,
                                        src1, dst1, base1, cnt1, csr1, E, eg);

  const int mmGrid = (N + 63) / 64;
  const int aggGrid = (N * 32 + 255) / 256;

  // layer 1 (A = x0 fp32, cvt inline)
  mm_mfma<128, false><<<mmGrid, 256, 0, stream>>>(x0, Wfb1, nullptr, nullptr, nullptr, 0.f,
                                                  h, P0, P1, N);
  agg_kernel<<<aggGrid, 256, 0, stream>>>(h, P0, P1, csr0, base0, csr1, base1, N);
  bnstats_kernel<<<256, 256, 0, stream>>>(h, stats1, N);

  // layer 2 (A = h fp32, BN1+leaky inline)
  mm_mfma<64, true><<<mmGrid, 256, 0, stream>>>(h, Wfb2, stats1, bn1_g, bn1_b, invN,
                                                h2, P0, P1, N);
  agg_kernel<<<aggGrid, 256, 0, stream>>>(h2, P0, P1, csr0, base0, csr1, base1, N);
  bnstats_kernel<<<256, 256, 0, stream>>>(h2, stats2, N);
  bnapply_kernel<<<(N * 16 + 255) / 256, 256, 0, stream>>>(h2, stats2, bn2_g, bn2_b, invN,
                                                           xc2, N);

  // output gather (dense coalesced widen-copy)
  gather_kernel<<<(2 * E * 32 + 255) / 256, 256, 0, stream>>>(
      xc2, src0, dst0, src1, dst1, (float*)d_out, E);
}